// Round 7
// baseline (332.060 us; speedup 1.0000x reference)
//
#include <hip/hip_runtime.h>
#include <math.h>

// ---------------------------------------------------------------------------
// FusionMoE R9: staged-bytes minimization under the measured law:
//   staging throughput ~= 11-12 B/cyc/CU, requires >=2 blocks/CU (grid>=512).
// - fusion split into fusion_gemm (split-K: grid (256,2), 64x256 tile, 48KB
//   LDS -> 3 blocks/CU, fp32 partials into P=H1 alias) + fusion_epi
//   (bias+LN+GELU+gate+lb, 32 rows/block, grid 512). B staged 410->205 MB.
// - combine reverted verbatim to R2/R7 form (grid 512; R8's 64-row form was
//   1 block/CU -> regressed).
// - prep (tiled transpose) and expert GEMMs (128x256) keep R8 forms.
// Math identical to R2 except fp32 K-half partial add (benign).
// ---------------------------------------------------------------------------

typedef unsigned short u16;
typedef unsigned int u32;
typedef __attribute__((ext_vector_type(8))) short bf16x8;
typedef __attribute__((ext_vector_type(4))) float f32x4;

__device__ __forceinline__ float bf2f(u16 u) {
    union { u32 i; float f; } v; v.i = ((u32)u) << 16; return v.f;
}
__device__ __forceinline__ u16 f2bf(float f) {  // RNE
    union { float f; u32 i; } v; v.f = f;
    u32 x = v.i;
    return (u16)((x + 0x7fffu + ((x >> 16) & 1u)) >> 16);
}
__device__ __forceinline__ float gelu_exact(float v) {
    return 0.5f * v * (1.0f + erff(v * 0.70710678118654752f));
}

typedef __attribute__((address_space(1))) void GV;
typedef __attribute__((address_space(3))) void SV;
__device__ __forceinline__ void gldlds(const void* g, void* l) {
    __builtin_amdgcn_global_load_lds((GV*)g, (SV*)l, 16, 0, 0);
}

// pack two f32 (bit-truncate) into one u32 of two bf16 (f0 low, f1 high)
__device__ __forceinline__ u32 pk2(u32 f0, u32 f1) {
    return __builtin_amdgcn_perm(f1, f0, 0x07060302);
}

// ----- staging helpers (XOR-8 swizzle), verified in R1 -----
// 256-thread variants (combine)
__device__ __forceinline__ void stageA64_R32(const u16* Ag, int lda, u16* As, int tid) {
    int s = tid;                        // 256 slots (32 rows x 8 chunks)
    int m = s >> 3, c = s & 7;
    gldlds(Ag + m * lda + (c ^ (m & 7)) * 8, As + s * 8);
}
__device__ __forceinline__ void stageB64(const u16* Bg, int ldb, u16* Bs, int tid) {
#pragma unroll
    for (int i = 0; i < 8; ++i) {
        int s = i * 256 + tid;          // 2048 slots (256 n-rows x 8 chunks)
        int n = s >> 3, c = s & 7;
        gldlds(Bg + n * ldb + (c ^ (n & 7)) * 8, Bs + s * 8);
    }
}
__device__ __forceinline__ void compute64_R32(const u16* As, const u16* Bs, f32x4 acc[2][4],
                                              int w, int l16, int quad) {
#pragma unroll
    for (int ks = 0; ks < 2; ++ks) {
        bf16x8 a[2];
#pragma unroll
        for (int mt = 0; mt < 2; ++mt) {
            int m = mt * 16 + l16;
            a[mt] = *(const bf16x8*)(As + m * 64 + (((ks * 4 + quad) ^ (m & 7)) << 3));
        }
#pragma unroll
        for (int nt = 0; nt < 4; ++nt) {
            int n = w * 64 + nt * 16 + l16;
            bf16x8 b = *(const bf16x8*)(Bs + n * 64 + (((ks * 4 + quad) ^ (n & 7)) << 3));
#pragma unroll
            for (int mt = 0; mt < 2; ++mt)
                acc[mt][nt] = __builtin_amdgcn_mfma_f32_16x16x32_bf16(a[mt], b, acc[mt][nt], 0, 0, 0);
        }
    }
}
// 512-thread variants (fusion_gemm / expert)
__device__ __forceinline__ void stageA128_512(const u16* Ag, int lda, u16* As, int tid) {
#pragma unroll
    for (int i = 0; i < 2; ++i) {
        int s = i * 512 + tid;          // 1024 slots (128 rows x 8 chunks)
        int m = s >> 3, c = s & 7;
        gldlds(Ag + m * lda + (c ^ (m & 7)) * 8, As + s * 8);
    }
}
__device__ __forceinline__ void stageB64_512(const u16* Bg, int ldb, u16* Bs, int tid) {
#pragma unroll
    for (int i = 0; i < 4; ++i) {
        int s = i * 512 + tid;          // 2048 slots (256 n-rows x 8 chunks)
        int n = s >> 3, c = s & 7;
        gldlds(Bg + n * ldb + (c ^ (n & 7)) * 8, Bs + s * 8);
    }
}
// 8-wave (2x4) 128-row compute (expert): wave (wrw,wc) owns 64x64
__device__ __forceinline__ void compute128_8w(const u16* As, const u16* Bs, f32x4 acc[4][4],
                                              int wrw, int wc, int l16, int quad) {
#pragma unroll
    for (int ks = 0; ks < 2; ++ks) {
        bf16x8 a[4];
#pragma unroll
        for (int mt = 0; mt < 4; ++mt) {
            int m = wrw * 64 + mt * 16 + l16;
            a[mt] = *(const bf16x8*)(As + m * 64 + (((ks * 4 + quad) ^ (m & 7)) << 3));
        }
#pragma unroll
        for (int nt = 0; nt < 4; ++nt) {
            int n = wc * 64 + nt * 16 + l16;
            bf16x8 b = *(const bf16x8*)(Bs + n * 64 + (((ks * 4 + quad) ^ (n & 7)) << 3));
#pragma unroll
            for (int mt = 0; mt < 4; ++mt)
                acc[mt][nt] = __builtin_amdgcn_mfma_f32_16x16x32_bf16(a[mt], b, acc[mt][nt], 0, 0, 0);
        }
    }
}

// ---------------------------------------------------------------------------
// K0: prep — tiled 32x32 LDS transpose (coalesced both sides) + lbacc zero.
// ---------------------------------------------------------------------------
__global__ __launch_bounds__(256) void prep_kernel(
    const float* __restrict__ Wf, const float* __restrict__ W1, const float* __restrict__ W2,
    const float* __restrict__ W3,
    u16* __restrict__ wft, u16* __restrict__ w1t, u16* __restrict__ w2t, u16* __restrict__ w3t,
    float* __restrict__ lbacc) {
    int b = blockIdx.x;
    int tid = threadIdx.x;
    const float* src; u16* dst; int K, N, kt, ntl;
    if (b < 400)      { src = Wf; dst = wft; K = 1600; N = 256; kt = b % 50; ntl = b / 50; }
    else if (b < 912) { int r = b - 400, e = r >> 7; r &= 127;
                        src = W1 + (size_t)e * 131072; dst = w1t + (size_t)e * 131072;
                        K = 256; N = 512; kt = r & 7; ntl = r >> 3; }
    else if (b < 1424){ int r = b - 912, e = r >> 7; r &= 127;
                        src = W2 + (size_t)e * 131072; dst = w2t + (size_t)e * 131072;
                        K = 512; N = 256; kt = r & 15; ntl = r >> 4; }
    else if (b < 1680){ int r = b - 1424, e = r >> 6; r &= 63;
                        src = W3 + (size_t)e * 65536; dst = w3t + (size_t)e * 65536;
                        K = 256; N = 256; kt = r & 7; ntl = r >> 3; }
    else { if (tid < 8) lbacc[tid] = 0.0f; return; }
    int k0 = kt * 32, n0 = ntl * 32;
    __shared__ float tl[32][33];
    int j = tid & 31, i0 = (tid >> 5) << 2;
#pragma unroll
    for (int ii = 0; ii < 4; ++ii)
        tl[i0 + ii][j] = src[(size_t)(k0 + i0 + ii) * N + n0 + j];
    __syncthreads();
#pragma unroll
    for (int ii = 0; ii < 4; ++ii)
        dst[(size_t)(n0 + i0 + ii) * K + k0 + j] = f2bf(tl[j][i0 + ii]);
}

// ---------------------------------------------------------------------------
// K1a: fusion_gemm — split-K. grid (256 m-tiles, 2 k-halves), 512t, 64x256
// tile, fp32 A direct (XOR-16), bf16 B. Writes fp32 partials to P.
// khalf 0: kits 0..11 (vis), khalf 1: kits 12..24 (lang+state).
// ---------------------------------------------------------------------------
__global__ __launch_bounds__(512, 4) void fusion_gemm_kernel(
    const float* __restrict__ vis, const float* __restrict__ lang, const float* __restrict__ state,
    const u16* __restrict__ BT, float* __restrict__ P) {
    __shared__ __align__(16) u32 Af[4096];   // 16KB: 64 rows x 16 f32-chunks (XOR-16)
    __shared__ __align__(16) u16 Bs[16384];  // 32KB: 256 n x 64 k bf16
    int tid = threadIdx.x;
    int w = tid >> 6, lane = tid & 63, quad = lane >> 4, l16 = lane & 15;
    int wrw = w >> 2, wc = w & 3;            // wave = (row-half, col-quarter)
    int m0 = blockIdx.x * 64;
    int khalf = blockIdx.y;
    int kbeg = khalf ? 12 : 0, kend = khalf ? 25 : 12;
    f32x4 acc[2][4] = {};

    for (int kit = kbeg; kit < kend; ++kit) {
        const float* base; int ld;
        if (kit < 12)      { base = vis   + (size_t)m0 * 768 + kit * 64;        ld = 768; }
        else if (kit < 24) { base = lang  + (size_t)m0 * 768 + (kit - 12) * 64; ld = 768; }
        else               { base = state + (size_t)m0 * 64;                    ld = 64; }
#pragma unroll
        for (int i = 0; i < 2; ++i) {        // A: 1024 slots of 16B (4 f32)
            int s = i * 512 + tid;
            int m = s >> 4, c = s & 15;
            gldlds(base + m * ld + (c ^ (m & 15)) * 4, Af + s * 4);
        }
        stageB64_512(BT + kit * 64, 1600, Bs, tid);   // 4 loads/thread
        __syncthreads();
#pragma unroll
        for (int ks = 0; ks < 2; ++ks) {
            bf16x8 a[2];
#pragma unroll
            for (int mt = 0; mt < 2; ++mt) {
                int m = wrw * 32 + mt * 16 + l16;
                int c0 = ks * 8 + quad * 2;
                const u32* rowp = Af + m * 64;
                uint4 f0 = *(const uint4*)(rowp + (c0 ^ (m & 15)) * 4);
                uint4 f1 = *(const uint4*)(rowp + ((c0 + 1) ^ (m & 15)) * 4);
                union { u32 u[4]; bf16x8 v; } pk;
                pk.u[0] = pk2(f0.x, f0.y); pk.u[1] = pk2(f0.z, f0.w);
                pk.u[2] = pk2(f1.x, f1.y); pk.u[3] = pk2(f1.z, f1.w);
                a[mt] = pk.v;
            }
#pragma unroll
            for (int nt = 0; nt < 4; ++nt) {
                int n = wc * 64 + nt * 16 + l16;
                bf16x8 b = *(const bf16x8*)(Bs + n * 64 + (((ks * 4 + quad) ^ (n & 7)) << 3));
#pragma unroll
                for (int mt = 0; mt < 2; ++mt)
                    acc[mt][nt] = __builtin_amdgcn_mfma_f32_16x16x32_bf16(a[mt], b, acc[mt][nt], 0, 0, 0);
            }
        }
        __syncthreads();
    }
    // write fp32 partials
#pragma unroll
    for (int mt = 0; mt < 2; ++mt)
#pragma unroll
        for (int r = 0; r < 4; ++r) {
            int row = wrw * 32 + mt * 16 + quad * 4 + r;
#pragma unroll
            for (int nt = 0; nt < 4; ++nt) {
                int col = wc * 64 + nt * 16 + l16;
                P[((size_t)khalf * 16384 + m0 + row) * 256 + col] = acc[mt][nt][r];
            }
        }
}

// ---------------------------------------------------------------------------
// K1b: fusion_epi — 32 rows/block, grid 512, 256t. Adds K-half partials +
// bias, LN, GELU -> xbf; gate (fp32 x) -> wr; lb atomics.
// Thread layout: row = tid>>3 (8 threads/row, same wave), cols (tid&7)*32..+31
// ---------------------------------------------------------------------------
__global__ __launch_bounds__(256) void fusion_epi_kernel(
    const float* __restrict__ P, const float* __restrict__ bfv_, const float* __restrict__ gf,
    const float* __restrict__ bfln, const float* __restrict__ Wg,
    u16* __restrict__ xbf, float* __restrict__ wr, float* __restrict__ lbacc) {
    __shared__ float sacc[8];
    int tid = threadIdx.x;
    int m0 = blockIdx.x * 32;
    int row = tid >> 3;                  // 0..31
    int cs = (tid & 7) * 32;             // col start
    if (tid < 8) sacc[tid] = 0.f;
    const float* p0 = P + ((size_t)(m0 + row)) * 256 + cs;
    const float* p1 = P + ((size_t)(16384 + m0 + row)) * 256 + cs;
    float v[32];
    float ss = 0.f, qq = 0.f;
#pragma unroll
    for (int j = 0; j < 32; j += 4) {
        float4 a = *(const float4*)(p0 + j);
        float4 b = *(const float4*)(p1 + j);
        float4 bb = *(const float4*)(bfv_ + cs + j);
        v[j + 0] = a.x + b.x + bb.x; v[j + 1] = a.y + b.y + bb.y;
        v[j + 2] = a.z + b.z + bb.z; v[j + 3] = a.w + b.w + bb.w;
        ss += v[j] + v[j + 1] + v[j + 2] + v[j + 3];
        qq += v[j] * v[j] + v[j + 1] * v[j + 1] + v[j + 2] * v[j + 2] + v[j + 3] * v[j + 3];
    }
#pragma unroll
    for (int d = 1; d < 8; d <<= 1) { ss += __shfl_xor(ss, d); qq += __shfl_xor(qq, d); }
    float mu = ss * (1.f / 256.f);
    float var = qq * (1.f / 256.f) - mu * mu;
    float rs = 1.f / sqrtf(var + 1e-5f);
    float pe0 = 0.f, pe1 = 0.f, pe2 = 0.f, pe3 = 0.f;
#pragma unroll
    for (int j = 0; j < 32; ++j) {
        float t = (v[j] - mu) * rs * gf[cs + j] + bfln[cs + j];
        float g = gelu_exact(t);
        v[j] = g;
        float4 wg = *(const float4*)(Wg + (cs + j) * 4);
        pe0 += g * wg.x; pe1 += g * wg.y; pe2 += g * wg.z; pe3 += g * wg.w;
    }
    // xbf store (u32 = 2 bf16)
    u16* xp = xbf + (size_t)(m0 + row) * 256 + cs;
#pragma unroll
    for (int j = 0; j < 32; j += 2) {
        u32 wv = (u32)f2bf(v[j]) | ((u32)f2bf(v[j + 1]) << 16);
        *(u32*)(xp + j) = wv;
    }
#pragma unroll
    for (int d = 1; d < 8; d <<= 1) {
        pe0 += __shfl_xor(pe0, d); pe1 += __shfl_xor(pe1, d);
        pe2 += __shfl_xor(pe2, d); pe3 += __shfl_xor(pe3, d);
    }
    __syncthreads();                     // sacc init visible
    if ((tid & 7) == 0) {
        float lg[4] = {pe0, pe1, pe2, pe3};
        float mx = fmaxf(fmaxf(lg[0], lg[1]), fmaxf(lg[2], lg[3]));
        float ex[4]; float Z = 0.f;
#pragma unroll
        for (int e = 0; e < 4; ++e) { ex[e] = expf(lg[e] - mx); Z += ex[e]; }
        int i0 = 0; float v0 = lg[0];
#pragma unroll
        for (int e = 1; e < 4; ++e) if (lg[e] > v0) { v0 = lg[e]; i0 = e; }
        int i1 = -1; float v1 = -1e30f;
#pragma unroll
        for (int e = 0; e < 4; ++e) if (e != i0 && lg[e] > v1) { v1 = lg[e]; i1 = e; }
        float t = expf(v1 - v0);
        float wA = 1.f / (1.f + t), wB = t / (1.f + t);
        float w4[4] = {0.f, 0.f, 0.f, 0.f};
        w4[i0] = wA; w4[i1] = wB;
#pragma unroll
        for (int e = 0; e < 4; ++e) wr[(size_t)(m0 + row) * 4 + e] = w4[e];
#pragma unroll
        for (int e = 0; e < 4; ++e) atomicAdd(&sacc[e], ex[e] / Z);
        atomicAdd(&sacc[4 + i0], 1.f);
        atomicAdd(&sacc[4 + i1], 1.f);
    }
    __syncthreads();
    if (tid < 8) atomicAdd(lbacc + tid, sacc[tid]);
}

// ---------------------------------------------------------------------------
// K2: expert GEMM + bias + GELU (R7/R8 form): 512 threads, 128x256 tile.
// ---------------------------------------------------------------------------
__global__ __launch_bounds__(512, 4) void expert_gemm_kernel(
    const u16* __restrict__ A, int lda, size_t aE,
    const u16* __restrict__ BT, size_t bE,
    const float* __restrict__ bias, int biasE,
    u16* __restrict__ outp, int ldo, size_t oE) {
    __shared__ __align__(16) u16 As[8192];       // 16KB: 128 rows x 64 k
    __shared__ __align__(16) u16 Bs[16384];      // 32KB: 256 n x 64 k
    int tid = threadIdx.x;
    int w = tid >> 6, lane = tid & 63, quad = lane >> 4, l16 = lane & 15;
    int wrw = w >> 2, wc = w & 3;
    int m0 = blockIdx.x * 128;
    int col0 = blockIdx.y * 256;
    int e = blockIdx.z;
    f32x4 acc[4][4] = {};
    const u16* Ag = A + e * aE + (size_t)m0 * lda;
    const u16* Bg = BT + e * bE + (size_t)col0 * lda;
    int kiters = lda >> 6;
    for (int kit = 0; kit < kiters; ++kit) {
        stageA128_512(Ag + kit * 64, lda, As, tid);
        stageB64_512(Bg + kit * 64, lda, Bs, tid);
        __syncthreads();
        compute128_8w(As, Bs, acc, wrw, wc, l16, quad);
        __syncthreads();
    }
#pragma unroll
    for (int nt = 0; nt < 4; ++nt) {
        int col = col0 + wc * 64 + nt * 16 + l16;
        float bvv = bias[e * biasE + col];
#pragma unroll
        for (int mt = 0; mt < 4; ++mt)
#pragma unroll
            for (int r = 0; r < 4; ++r) {
                int row = m0 + wrw * 64 + mt * 16 + quad * 4 + r;
                outp[e * oE + (size_t)row * ldo + col] = f2bf(gelu_exact(acc[mt][nt][r] + bvv));
            }
    }
}

// ---------------------------------------------------------------------------
// K3: combine — R2/R7 form verbatim (measured best): 256t, 32-row tiles,
// grid 512, single-buffer, xs in LDS.
// ---------------------------------------------------------------------------
__global__ __launch_bounds__(256) void combine_kernel(
    const u16* __restrict__ h2, const u16* __restrict__ W3T,
    const float* __restrict__ b3, const float* __restrict__ eg, const float* __restrict__ eb,
    const u16* __restrict__ xbf, const float* __restrict__ wr,
    const float* __restrict__ lbacc, float* __restrict__ outp) {
    __shared__ __align__(16) u16 As[2048];    // 4KB: 32 rows x 64 k
    __shared__ __align__(16) u16 Bs[16384];   // 32KB
    __shared__ __align__(16) u16 xs[8192];    // 16KB: 32 rows x 256 bf16
    __shared__ float wl[128];
    int tid = threadIdx.x;
    int w = tid >> 6, lane = tid & 63, quad = lane >> 4, l16 = lane & 15;
    int m0 = blockIdx.x * 32;
    if (blockIdx.x == 0 && tid == 0) {        // lb_loss (lbacc complete: fusion done)
        float lb = 0.f;
#pragma unroll
        for (int e = 0; e < 4; ++e)
            lb += (lbacc[4 + e] / 32768.f) * (lbacc[e] / 16384.f);
        outp[4194304] = 4.f * lb;
    }
#pragma unroll
    for (int i = 0; i < 4; ++i) {
        int s = i * 256 + tid;
        *(uint4*)(xs + s * 8) = *(const uint4*)(xbf + (size_t)m0 * 256 + s * 8);
    }
    if (tid < 128) wl[tid] = wr[(size_t)m0 * 4 + tid];
    float2* red = (float2*)As;               // alias (barrier-guarded)
    float* muv = (float*)((char*)As + 1024);
    float* rsv = (float*)((char*)As + 1152);
    f32x4 oacc[2][4] = {};
    for (int e = 0; e < 4; ++e) {
        __syncthreads();                     // covers xs/wl (e=0), red reuse (e>0)
        f32x4 acc[2][4] = {};
        const u16* Ag = h2 + ((size_t)e * 16384 + m0) * 256;
        const u16* Bg = W3T + (size_t)e * 65536;
        for (int kit = 0; kit < 4; ++kit) {
            stageA64_R32(Ag + kit * 64, 256, As, tid);
            stageB64(Bg + kit * 64, 256, Bs, tid);
            __syncthreads();
            compute64_R32(As, Bs, acc, w, l16, quad);
            __syncthreads();
        }
        float b3v[4], egv[4], ebv[4];
#pragma unroll
        for (int nt = 0; nt < 4; ++nt) {
            int col = w * 64 + nt * 16 + l16;
            b3v[nt] = b3[e * 256 + col]; egv[nt] = eg[e * 256 + col]; ebv[nt] = eb[e * 256 + col];
        }
#pragma unroll
        for (int mt = 0; mt < 2; ++mt)
#pragma unroll
            for (int r = 0; r < 4; ++r) {
                int rl = mt * 16 + quad * 4 + r;
                float ss = 0.f, qq = 0.f;
#pragma unroll
                for (int nt = 0; nt < 4; ++nt) {
                    int col = w * 64 + nt * 16 + l16;
                    float v = acc[mt][nt][r] + b3v[nt] + bf2f(xs[rl * 256 + col]);
                    acc[mt][nt][r] = v;
                    ss += v; qq += v * v;
                }
#pragma unroll
                for (int d = 1; d < 16; d <<= 1) { ss += __shfl_xor(ss, d); qq += __shfl_xor(qq, d); }
                if (l16 == 0) red[w * 32 + rl] = make_float2(ss, qq);
            }
        __syncthreads();
        if (tid < 32) {
            float ss = 0.f, qq = 0.f;
#pragma unroll
            for (int ww = 0; ww < 4; ++ww) { float2 t = red[ww * 32 + tid]; ss += t.x; qq += t.y; }
            float mu = ss * (1.f / 256.f);
            float var = qq * (1.f / 256.f) - mu * mu;
            muv[tid] = mu;
            rsv[tid] = 1.f / sqrtf(var + 1e-5f);
        }
        __syncthreads();
#pragma unroll
        for (int mt = 0; mt < 2; ++mt)
#pragma unroll
            for (int r = 0; r < 4; ++r) {
                int rl = mt * 16 + quad * 4 + r;
                float mu = muv[rl], rs = rsv[rl], we = wl[rl * 4 + e];
#pragma unroll
                for (int nt = 0; nt < 4; ++nt) {
                    float y = (acc[mt][nt][r] - mu) * rs * egv[nt] + ebv[nt];
                    oacc[mt][nt][r] += we * y;
                }
            }
    }
#pragma unroll
    for (int mt = 0; mt < 2; ++mt)
#pragma unroll
        for (int r = 0; r < 4; ++r) {
            int rl = mt * 16 + quad * 4 + r;
#pragma unroll
            for (int nt = 0; nt < 4; ++nt) {
                int col = w * 64 + nt * 16 + l16;
                outp[(size_t)(m0 + rl) * 256 + col] = oacc[mt][nt][r];
            }
        }
}

// ---------------------------------------------------------------------------
extern "C" void kernel_launch(void* const* d_in, const int* in_sizes, int n_in,
                              void* d_out, int out_size, void* d_ws, size_t ws_size,
                              hipStream_t stream) {
    const float* vis   = (const float*)d_in[0];
    const float* lang  = (const float*)d_in[1];
    const float* state = (const float*)d_in[2];
    const float* Wf    = (const float*)d_in[3];
    const float* bf_   = (const float*)d_in[4];
    const float* gf    = (const float*)d_in[5];
    const float* bfln  = (const float*)d_in[6];
    const float* Wg    = (const float*)d_in[7];
    const float* W1    = (const float*)d_in[8];
    const float* b1    = (const float*)d_in[9];
    const float* W2    = (const float*)d_in[10];
    const float* b2    = (const float*)d_in[11];
    const float* W3    = (const float*)d_in[12];
    const float* b3    = (const float*)d_in[13];
    const float* eg    = (const float*)d_in[14];
    const float* eb    = (const float*)d_in[15];
    float* outp = (float*)d_out;

    char* ws = (char*)d_ws;
    size_t off = 0;
    float* lbacc = (float*)(ws + off); off += 256;
    u16* WFT  = (u16*)(ws + off); off += 819200UL;     // WfT [256][1600]
    u16* W1T  = (u16*)(ws + off); off += 1048576UL;    // [E][512][256]
    u16* W2T  = (u16*)(ws + off); off += 1048576UL;    // [E][256][512]
    u16* W3T  = (u16*)(ws + off); off += 524288UL;     // [E][256][256]
    u16* XBF  = (u16*)(ws + off); off += 8388608UL;    // x bf16 [B][256]
    float* WR = (float*)(ws + off); off += 262144UL;   // gate weights [B][4]
    u16* H1   = (u16*)(ws + off); off += 67108864UL;   // [E][B][512]
    u16* H2   = (u16*)(ws + off); off += 33554432UL;   // [E][B][256]
    if (ws_size < off) return;
    float* P = (float*)H1;   // 32 MB fp32 partials alias H1 (consumed by
                             // fusion_epi before eg1 writes H1)

    prep_kernel<<<1681, 256, 0, stream>>>(Wf, W1, W2, W3, WFT, W1T, W2T, W3T, lbacc);
    fusion_gemm_kernel<<<dim3(256, 2), 512, 0, stream>>>(vis, lang, state, WFT, P);
    fusion_epi_kernel<<<512, 256, 0, stream>>>(P, bf_, gf, bfln, Wg, XBF, WR, lbacc);
    expert_gemm_kernel<<<dim3(128, 2, 4), 512, 0, stream>>>(
        XBF, 256, 0, W1T, 131072, b1, 512, H1, 512, 8388608UL);
    expert_gemm_kernel<<<dim3(128, 1, 4), 512, 0, stream>>>(
        H1, 512, 8388608UL, W2T, 131072, b2, 256, H2, 256, 4194304UL);
    combine_kernel<<<512, 256, 0, stream>>>(H2, W3T, b3, eg, eb, XBF, WR, lbacc, outp);
}

// Round 8
// 301.498 us; speedup vs baseline: 1.1014x; 1.1014x over previous
//
#include <hip/hip_runtime.h>
#include <math.h>

// ---------------------------------------------------------------------------
// FusionMoE R10: recombination of measured-best forms + eg write-path fix.
// fusion = R6 form (512x512t, 32x256, 2 blocks/CU, 72-74us measured).
// combine = R2 form (512x256t, 32-row). prep = tiled transpose.
// expert_gemm = 128x256 (R7) + NEW LDS-bounce epilogue: GELU'd bf16 bounced
// through Bs (XOR-swizzled), stored as 64B contiguous chunks -> full-line
// HBM writes (was 64 scalar 2B stores/thread, 28% write amplification).
// Math identical to R2.
// ---------------------------------------------------------------------------

typedef unsigned short u16;
typedef unsigned int u32;
typedef __attribute__((ext_vector_type(8))) short bf16x8;
typedef __attribute__((ext_vector_type(4))) float f32x4;

__device__ __forceinline__ float bf2f(u16 u) {
    union { u32 i; float f; } v; v.i = ((u32)u) << 16; return v.f;
}
__device__ __forceinline__ u16 f2bf(float f) {  // RNE
    union { float f; u32 i; } v; v.f = f;
    u32 x = v.i;
    return (u16)((x + 0x7fffu + ((x >> 16) & 1u)) >> 16);
}
__device__ __forceinline__ float gelu_exact(float v) {
    return 0.5f * v * (1.0f + erff(v * 0.70710678118654752f));
}

typedef __attribute__((address_space(1))) void GV;
typedef __attribute__((address_space(3))) void SV;
__device__ __forceinline__ void gldlds(const void* g, void* l) {
    __builtin_amdgcn_global_load_lds((GV*)g, (SV*)l, 16, 0, 0);
}

// pack two f32 (bit-truncate) into one u32 of two bf16 (f0 low, f1 high)
__device__ __forceinline__ u32 pk2(u32 f0, u32 f1) {
    return __builtin_amdgcn_perm(f1, f0, 0x07060302);
}

// ----- staging helpers (XOR-8 swizzle), verified in R1 -----
// 256-thread variants (combine)
__device__ __forceinline__ void stageA64_R32(const u16* Ag, int lda, u16* As, int tid) {
    int s = tid;                        // 256 slots (32 rows x 8 chunks)
    int m = s >> 3, c = s & 7;
    gldlds(Ag + m * lda + (c ^ (m & 7)) * 8, As + s * 8);
}
__device__ __forceinline__ void stageB64(const u16* Bg, int ldb, u16* Bs, int tid) {
#pragma unroll
    for (int i = 0; i < 8; ++i) {
        int s = i * 256 + tid;          // 2048 slots (256 n-rows x 8 chunks)
        int n = s >> 3, c = s & 7;
        gldlds(Bg + n * ldb + (c ^ (n & 7)) * 8, Bs + s * 8);
    }
}
__device__ __forceinline__ void compute64_R32(const u16* As, const u16* Bs, f32x4 acc[2][4],
                                              int w, int l16, int quad) {
#pragma unroll
    for (int ks = 0; ks < 2; ++ks) {
        bf16x8 a[2];
#pragma unroll
        for (int mt = 0; mt < 2; ++mt) {
            int m = mt * 16 + l16;
            a[mt] = *(const bf16x8*)(As + m * 64 + (((ks * 4 + quad) ^ (m & 7)) << 3));
        }
#pragma unroll
        for (int nt = 0; nt < 4; ++nt) {
            int n = w * 64 + nt * 16 + l16;
            bf16x8 b = *(const bf16x8*)(Bs + n * 64 + (((ks * 4 + quad) ^ (n & 7)) << 3));
#pragma unroll
            for (int mt = 0; mt < 2; ++mt)
                acc[mt][nt] = __builtin_amdgcn_mfma_f32_16x16x32_bf16(a[mt], b, acc[mt][nt], 0, 0, 0);
        }
    }
}
// 512-thread variants (fusion / expert)
__device__ __forceinline__ void stageA128_512(const u16* Ag, int lda, u16* As, int tid) {
#pragma unroll
    for (int i = 0; i < 2; ++i) {
        int s = i * 512 + tid;          // 1024 slots (128 rows x 8 chunks)
        int m = s >> 3, c = s & 7;
        gldlds(Ag + m * lda + (c ^ (m & 7)) * 8, As + s * 8);
    }
}
__device__ __forceinline__ void stageB64_512(const u16* Bg, int ldb, u16* Bs, int tid) {
#pragma unroll
    for (int i = 0; i < 4; ++i) {
        int s = i * 512 + tid;          // 2048 slots (256 n-rows x 8 chunks)
        int n = s >> 3, c = s & 7;
        gldlds(Bg + n * ldb + (c ^ (n & 7)) * 8, Bs + s * 8);
    }
}
// 8-wave (2x4) 128-row compute (expert): wave (wrw,wc) owns 64x64
__device__ __forceinline__ void compute128_8w(const u16* As, const u16* Bs, f32x4 acc[4][4],
                                              int wrw, int wc, int l16, int quad) {
#pragma unroll
    for (int ks = 0; ks < 2; ++ks) {
        bf16x8 a[4];
#pragma unroll
        for (int mt = 0; mt < 4; ++mt) {
            int m = wrw * 64 + mt * 16 + l16;
            a[mt] = *(const bf16x8*)(As + m * 64 + (((ks * 4 + quad) ^ (m & 7)) << 3));
        }
#pragma unroll
        for (int nt = 0; nt < 4; ++nt) {
            int n = wc * 64 + nt * 16 + l16;
            bf16x8 b = *(const bf16x8*)(Bs + n * 64 + (((ks * 4 + quad) ^ (n & 7)) << 3));
#pragma unroll
            for (int mt = 0; mt < 4; ++mt)
                acc[mt][nt] = __builtin_amdgcn_mfma_f32_16x16x32_bf16(a[mt], b, acc[mt][nt], 0, 0, 0);
        }
    }
}

// ---------------------------------------------------------------------------
// K0: prep — tiled 32x32 LDS transpose (coalesced both sides) + lbacc zero.
// ---------------------------------------------------------------------------
__global__ __launch_bounds__(256) void prep_kernel(
    const float* __restrict__ Wf, const float* __restrict__ W1, const float* __restrict__ W2,
    const float* __restrict__ W3,
    u16* __restrict__ wft, u16* __restrict__ w1t, u16* __restrict__ w2t, u16* __restrict__ w3t,
    float* __restrict__ lbacc) {
    int b = blockIdx.x;
    int tid = threadIdx.x;
    const float* src; u16* dst; int K, N, kt, ntl;
    if (b < 400)      { src = Wf; dst = wft; K = 1600; N = 256; kt = b % 50; ntl = b / 50; }
    else if (b < 912) { int r = b - 400, e = r >> 7; r &= 127;
                        src = W1 + (size_t)e * 131072; dst = w1t + (size_t)e * 131072;
                        K = 256; N = 512; kt = r & 7; ntl = r >> 3; }
    else if (b < 1424){ int r = b - 912, e = r >> 7; r &= 127;
                        src = W2 + (size_t)e * 131072; dst = w2t + (size_t)e * 131072;
                        K = 512; N = 256; kt = r & 15; ntl = r >> 4; }
    else if (b < 1680){ int r = b - 1424, e = r >> 6; r &= 63;
                        src = W3 + (size_t)e * 65536; dst = w3t + (size_t)e * 65536;
                        K = 256; N = 256; kt = r & 7; ntl = r >> 3; }
    else { if (tid < 8) lbacc[tid] = 0.0f; return; }
    int k0 = kt * 32, n0 = ntl * 32;
    __shared__ float tl[32][33];
    int j = tid & 31, i0 = (tid >> 5) << 2;
#pragma unroll
    for (int ii = 0; ii < 4; ++ii)
        tl[i0 + ii][j] = src[(size_t)(k0 + i0 + ii) * N + n0 + j];
    __syncthreads();
#pragma unroll
    for (int ii = 0; ii < 4; ++ii)
        dst[(size_t)(n0 + i0 + ii) * K + k0 + j] = f2bf(tl[j][i0 + ii]);
}

// ---------------------------------------------------------------------------
// K1: fusion — R6 form verbatim: 512 threads (8 waves), 32x256 tile, grid 512,
// single-buffer. Epilogue: bias+LN+GELU -> xbf, fused gate -> wr + lb atomics.
// ---------------------------------------------------------------------------
__global__ __launch_bounds__(512, 4) void fusion_kernel(
    const float* __restrict__ vis, const float* __restrict__ lang, const float* __restrict__ state,
    const u16* __restrict__ BT, const float* __restrict__ bfv_, const float* __restrict__ gf,
    const float* __restrict__ bfln, const float* __restrict__ Wg,
    u16* __restrict__ xbf, float* __restrict__ wr, float* __restrict__ lbacc) {
    __shared__ __align__(16) u32 Af[2048];   // 8KB: 32 rows x 16 f32-chunks (XOR-16)
    __shared__ __align__(16) u16 Bs[16384];  // 32KB: 256 n x 64 k bf16
    int tid = threadIdx.x;
    int w = tid >> 6, lane = tid & 63, quad = lane >> 4, l16 = lane & 15;
    int m0 = blockIdx.x * 32;
    f32x4 acc[2][2] = {};

    for (int kit = 0; kit < 25; ++kit) {
        const float* base; int ld;
        if (kit < 12)      { base = vis   + (size_t)m0 * 768 + kit * 64;        ld = 768; }
        else if (kit < 24) { base = lang  + (size_t)m0 * 768 + (kit - 12) * 64; ld = 768; }
        else               { base = state + (size_t)m0 * 64;                    ld = 64; }
        {   // A: 512 slots of 16B (4 f32), 1 per thread
            int s = tid;
            int m = s >> 4, c = s & 15;
            gldlds(base + m * ld + (c ^ (m & 15)) * 4, Af + s * 4);
        }
        stageB64_512(BT + kit * 64, 1600, Bs, tid);   // 4 loads/thread
        __syncthreads();
#pragma unroll
        for (int ks = 0; ks < 2; ++ks) {
            bf16x8 a[2];
#pragma unroll
            for (int mt = 0; mt < 2; ++mt) {
                int m = mt * 16 + l16;
                int c0 = ks * 8 + quad * 2;
                const u32* rowp = Af + m * 64;
                uint4 f0 = *(const uint4*)(rowp + (c0 ^ (m & 15)) * 4);
                uint4 f1 = *(const uint4*)(rowp + ((c0 + 1) ^ (m & 15)) * 4);
                union { u32 u[4]; bf16x8 v; } pk;
                pk.u[0] = pk2(f0.x, f0.y); pk.u[1] = pk2(f0.z, f0.w);
                pk.u[2] = pk2(f1.x, f1.y); pk.u[3] = pk2(f1.z, f1.w);
                a[mt] = pk.v;
            }
#pragma unroll
            for (int nt = 0; nt < 2; ++nt) {
                int n = w * 32 + nt * 16 + l16;
                bf16x8 b = *(const bf16x8*)(Bs + n * 64 + (((ks * 4 + quad) ^ (n & 7)) << 3));
#pragma unroll
                for (int mt = 0; mt < 2; ++mt)
                    acc[mt][nt] = __builtin_amdgcn_mfma_f32_16x16x32_bf16(a[mt], b, acc[mt][nt], 0, 0, 0);
            }
        }
        __syncthreads();
    }

    // ---- epilogue: bias, LN, GELU, xbf store, fused gate ----
    float2* red  = (float2*)Af;            // 256 float2 (w*32+rl)  Af[0..511]
    float*  muv  = (float*)(Af + 512);     // 32
    float*  rsv  = (float*)(Af + 544);     // 32
    float*  gred = (float*)(Af + 576);     // 1024: [w][rl][e]      Af[576..1599]
    float*  sacc = (float*)(Af + 1600);    // 8

    float bv[2], gvv[2], blv[2]; float4 wgv[2];
#pragma unroll
    for (int nt = 0; nt < 2; ++nt) {
        int col = w * 32 + nt * 16 + l16;
        bv[nt] = bfv_[col]; gvv[nt] = gf[col]; blv[nt] = bfln[col];
        wgv[nt] = *(const float4*)(Wg + col * 4);
    }
    if (tid < 8) sacc[tid] = 0.f;
#pragma unroll
    for (int mt = 0; mt < 2; ++mt)
#pragma unroll
        for (int r = 0; r < 4; ++r) {
            float ss = 0.f, qq = 0.f;
#pragma unroll
            for (int nt = 0; nt < 2; ++nt) {
                float v = acc[mt][nt][r] + bv[nt];
                acc[mt][nt][r] = v;
                ss += v; qq += v * v;
            }
#pragma unroll
            for (int d = 1; d < 16; d <<= 1) { ss += __shfl_xor(ss, d); qq += __shfl_xor(qq, d); }
            if (l16 == 0) red[w * 32 + mt * 16 + quad * 4 + r] = make_float2(ss, qq);
        }
    __syncthreads();
    if (tid < 32) {
        float ss = 0.f, qq = 0.f;
#pragma unroll
        for (int ww = 0; ww < 8; ++ww) { float2 t = red[ww * 32 + tid]; ss += t.x; qq += t.y; }
        float mu = ss * (1.f / 256.f);
        float var = qq * (1.f / 256.f) - mu * mu;
        muv[tid] = mu;
        rsv[tid] = 1.f / sqrtf(var + 1e-5f);
    }
    __syncthreads();
#pragma unroll
    for (int mt = 0; mt < 2; ++mt)
#pragma unroll
        for (int r = 0; r < 4; ++r) {
            int rl = mt * 16 + quad * 4 + r;
            float mu = muv[rl], rs = rsv[rl];
#pragma unroll
            for (int nt = 0; nt < 2; ++nt) {
                int col = w * 32 + nt * 16 + l16;
                float t = (acc[mt][nt][r] - mu) * rs * gvv[nt] + blv[nt];
                float g = gelu_exact(t);
                acc[mt][nt][r] = g;
                xbf[(size_t)(m0 + rl) * 256 + col] = f2bf(g);
            }
        }
    // gate partials (fp32 x, pre-bf16-truncation)
#pragma unroll
    for (int mt = 0; mt < 2; ++mt)
#pragma unroll
        for (int r = 0; r < 4; ++r) {
            int rl = mt * 16 + quad * 4 + r;
            float p0 = 0.f, p1 = 0.f, p2 = 0.f, p3 = 0.f;
#pragma unroll
            for (int nt = 0; nt < 2; ++nt) {
                float g = acc[mt][nt][r];
                p0 += g * wgv[nt].x; p1 += g * wgv[nt].y;
                p2 += g * wgv[nt].z; p3 += g * wgv[nt].w;
            }
#pragma unroll
            for (int d = 1; d < 16; d <<= 1) {
                p0 += __shfl_xor(p0, d); p1 += __shfl_xor(p1, d);
                p2 += __shfl_xor(p2, d); p3 += __shfl_xor(p3, d);
            }
            if (l16 == 0) {
                float* gp = gred + w * 128 + rl * 4;
                gp[0] = p0; gp[1] = p1; gp[2] = p2; gp[3] = p3;
            }
        }
    __syncthreads();
    if (tid < 32) {
        int row = tid;
        float lg[4];
#pragma unroll
        for (int e = 0; e < 4; ++e) {
            float s = 0.f;
#pragma unroll
            for (int ww = 0; ww < 8; ++ww) s += gred[ww * 128 + row * 4 + e];
            lg[e] = s;
        }
        float mx = fmaxf(fmaxf(lg[0], lg[1]), fmaxf(lg[2], lg[3]));
        float ex[4]; float Z = 0.f;
#pragma unroll
        for (int e = 0; e < 4; ++e) { ex[e] = expf(lg[e] - mx); Z += ex[e]; }
        int i0 = 0; float v0 = lg[0];
#pragma unroll
        for (int e = 1; e < 4; ++e) if (lg[e] > v0) { v0 = lg[e]; i0 = e; }
        int i1 = -1; float v1 = -1e30f;
#pragma unroll
        for (int e = 0; e < 4; ++e) if (e != i0 && lg[e] > v1) { v1 = lg[e]; i1 = e; }
        float t = expf(v1 - v0);
        float wA = 1.f / (1.f + t), wB = t / (1.f + t);
        float w4[4] = {0.f, 0.f, 0.f, 0.f};
        w4[i0] = wA; w4[i1] = wB;
#pragma unroll
        for (int e = 0; e < 4; ++e) wr[(size_t)(m0 + row) * 4 + e] = w4[e];
#pragma unroll
        for (int e = 0; e < 4; ++e) atomicAdd(&sacc[e], ex[e] / Z);
        atomicAdd(&sacc[4 + i0], 1.f);
        atomicAdd(&sacc[4 + i1], 1.f);
    }
    __syncthreads();
    if (tid < 8) atomicAdd(lbacc + tid, sacc[tid]);
}

// ---------------------------------------------------------------------------
// K2: expert GEMM + bias + GELU: 512 threads, 128x256 tile, LDS-bounce
// epilogue (full-line writes). Bounce uses Bs (32KB) in two 64-row halves.
// ---------------------------------------------------------------------------
__global__ __launch_bounds__(512, 4) void expert_gemm_kernel(
    const u16* __restrict__ A, int lda, size_t aE,
    const u16* __restrict__ BT, size_t bE,
    const float* __restrict__ bias, int biasE,
    u16* __restrict__ outp, int ldo, size_t oE) {
    __shared__ __align__(16) u16 As[8192];       // 16KB: 128 rows x 64 k
    __shared__ __align__(16) u16 Bs[16384];      // 32KB: 256 n x 64 k / bounce
    int tid = threadIdx.x;
    int w = tid >> 6, lane = tid & 63, quad = lane >> 4, l16 = lane & 15;
    int wrw = w >> 2, wc = w & 3;
    int m0 = blockIdx.x * 128;
    int col0 = blockIdx.y * 256;
    int e = blockIdx.z;
    f32x4 acc[4][4] = {};
    const u16* Ag = A + e * aE + (size_t)m0 * lda;
    const u16* Bg = BT + e * bE + (size_t)col0 * lda;
    int kiters = lda >> 6;
    for (int kit = 0; kit < kiters; ++kit) {
        stageA128_512(Ag + kit * 64, lda, As, tid);
        stageB64_512(Bg + kit * 64, lda, Bs, tid);
        __syncthreads();
        compute128_8w(As, Bs, acc, wrw, wc, l16, quad);
        __syncthreads();
    }
    // ---- epilogue: GELU -> bf16 via LDS bounce -> full-line stores ----
    float bvv[4];
#pragma unroll
    for (int nt = 0; nt < 4; ++nt)
        bvv[nt] = bias[e * biasE + col0 + wc * 64 + nt * 16 + l16];
#pragma unroll
    for (int h = 0; h < 2; ++h) {                // mt pairs {0,1}, {2,3}
#pragma unroll
        for (int mt2 = 0; mt2 < 2; ++mt2) {
            int mt = h * 2 + mt2;
#pragma unroll
            for (int r = 0; r < 4; ++r) {
                int vrow = wrw * 32 + mt2 * 16 + quad * 4 + r;   // 0..63
#pragma unroll
                for (int nt = 0; nt < 4; ++nt) {
                    int col = wc * 64 + nt * 16 + l16;
                    float g = gelu_exact(acc[mt][nt][r] + bvv[nt]);
                    Bs[vrow * 256 + (col ^ ((vrow & 7) << 5))] = f2bf(g);
                }
            }
        }
        __syncthreads();
        {   // reader: 512 threads, 64B contiguous each (8 threads/row)
            int vrow = tid >> 3, cc = tid & 7;
            int base = vrow * 256 + ((cc ^ (vrow & 7)) << 5);
            int grow = m0 + h * 32 + (vrow >> 5) * 64 + (vrow & 31);
            u16* op = outp + e * oE + (size_t)grow * ldo + col0 + cc * 32;
#pragma unroll
            for (int j = 0; j < 4; ++j)
                *(uint4*)(op + j * 8) = *(const uint4*)(Bs + base + j * 8);
        }
        if (h == 0) __syncthreads();             // Bs reuse for second half
    }
}

// ---------------------------------------------------------------------------
// K3: combine — R2 form verbatim (measured best): 256t, 32-row tiles,
// grid 512, single-buffer, xs in LDS.
// ---------------------------------------------------------------------------
__global__ __launch_bounds__(256) void combine_kernel(
    const u16* __restrict__ h2, const u16* __restrict__ W3T,
    const float* __restrict__ b3, const float* __restrict__ eg, const float* __restrict__ eb,
    const u16* __restrict__ xbf, const float* __restrict__ wr,
    const float* __restrict__ lbacc, float* __restrict__ outp) {
    __shared__ __align__(16) u16 As[2048];    // 4KB: 32 rows x 64 k
    __shared__ __align__(16) u16 Bs[16384];   // 32KB
    __shared__ __align__(16) u16 xs[8192];    // 16KB: 32 rows x 256 bf16
    __shared__ float wl[128];
    int tid = threadIdx.x;
    int w = tid >> 6, lane = tid & 63, quad = lane >> 4, l16 = lane & 15;
    int m0 = blockIdx.x * 32;
    if (blockIdx.x == 0 && tid == 0) {        // lb_loss (lbacc complete: fusion done)
        float lb = 0.f;
#pragma unroll
        for (int e = 0; e < 4; ++e)
            lb += (lbacc[4 + e] / 32768.f) * (lbacc[e] / 16384.f);
        outp[4194304] = 4.f * lb;
    }
#pragma unroll
    for (int i = 0; i < 4; ++i) {
        int s = i * 256 + tid;
        *(uint4*)(xs + s * 8) = *(const uint4*)(xbf + (size_t)m0 * 256 + s * 8);
    }
    if (tid < 128) wl[tid] = wr[(size_t)m0 * 4 + tid];
    float2* red = (float2*)As;               // alias (barrier-guarded)
    float* muv = (float*)((char*)As + 1024);
    float* rsv = (float*)((char*)As + 1152);
    f32x4 oacc[2][4] = {};
    for (int e = 0; e < 4; ++e) {
        __syncthreads();                     // covers xs/wl (e=0), red reuse (e>0)
        f32x4 acc[2][4] = {};
        const u16* Ag = h2 + ((size_t)e * 16384 + m0) * 256;
        const u16* Bg = W3T + (size_t)e * 65536;
        for (int kit = 0; kit < 4; ++kit) {
            stageA64_R32(Ag + kit * 64, 256, As, tid);
            stageB64(Bg + kit * 64, 256, Bs, tid);
            __syncthreads();
            compute64_R32(As, Bs, acc, w, l16, quad);
            __syncthreads();
        }
        float b3v[4], egv[4], ebv[4];
#pragma unroll
        for (int nt = 0; nt < 4; ++nt) {
            int col = w * 64 + nt * 16 + l16;
            b3v[nt] = b3[e * 256 + col]; egv[nt] = eg[e * 256 + col]; ebv[nt] = eb[e * 256 + col];
        }
#pragma unroll
        for (int mt = 0; mt < 2; ++mt)
#pragma unroll
            for (int r = 0; r < 4; ++r) {
                int rl = mt * 16 + quad * 4 + r;
                float ss = 0.f, qq = 0.f;
#pragma unroll
                for (int nt = 0; nt < 4; ++nt) {
                    int col = w * 64 + nt * 16 + l16;
                    float v = acc[mt][nt][r] + b3v[nt] + bf2f(xs[rl * 256 + col]);
                    acc[mt][nt][r] = v;
                    ss += v; qq += v * v;
                }
#pragma unroll
                for (int d = 1; d < 16; d <<= 1) { ss += __shfl_xor(ss, d); qq += __shfl_xor(qq, d); }
                if (l16 == 0) red[w * 32 + rl] = make_float2(ss, qq);
            }
        __syncthreads();
        if (tid < 32) {
            float ss = 0.f, qq = 0.f;
#pragma unroll
            for (int ww = 0; ww < 4; ++ww) { float2 t = red[ww * 32 + tid]; ss += t.x; qq += t.y; }
            float mu = ss * (1.f / 256.f);
            float var = qq * (1.f / 256.f) - mu * mu;
            muv[tid] = mu;
            rsv[tid] = 1.f / sqrtf(var + 1e-5f);
        }
        __syncthreads();
#pragma unroll
        for (int mt = 0; mt < 2; ++mt)
#pragma unroll
            for (int r = 0; r < 4; ++r) {
                int rl = mt * 16 + quad * 4 + r;
                float mu = muv[rl], rs = rsv[rl], we = wl[rl * 4 + e];
#pragma unroll
                for (int nt = 0; nt < 4; ++nt) {
                    float y = (acc[mt][nt][r] - mu) * rs * egv[nt] + ebv[nt];
                    oacc[mt][nt][r] += we * y;
                }
            }
    }
#pragma unroll
    for (int mt = 0; mt < 2; ++mt)
#pragma unroll
        for (int r = 0; r < 4; ++r) {
            int rl = mt * 16 + quad * 4 + r;
#pragma unroll
            for (int nt = 0; nt < 4; ++nt) {
                int col = w * 64 + nt * 16 + l16;
                outp[(size_t)(m0 + rl) * 256 + col] = oacc[mt][nt][r];
            }
        }
}

// ---------------------------------------------------------------------------
extern "C" void kernel_launch(void* const* d_in, const int* in_sizes, int n_in,
                              void* d_out, int out_size, void* d_ws, size_t ws_size,
                              hipStream_t stream) {
    const float* vis   = (const float*)d_in[0];
    const float* lang  = (const float*)d_in[1];
    const float* state = (const float*)d_in[2];
    const float* Wf    = (const float*)d_in[3];
    const float* bf_   = (const float*)d_in[4];
    const float* gf    = (const float*)d_in[5];
    const float* bfln  = (const float*)d_in[6];
    const float* Wg    = (const float*)d_in[7];
    const float* W1    = (const float*)d_in[8];
    const float* b1    = (const float*)d_in[9];
    const float* W2    = (const float*)d_in[10];
    const float* b2    = (const float*)d_in[11];
    const float* W3    = (const float*)d_in[12];
    const float* b3    = (const float*)d_in[13];
    const float* eg    = (const float*)d_in[14];
    const float* eb    = (const float*)d_in[15];
    float* outp = (float*)d_out;

    char* ws = (char*)d_ws;
    size_t off = 0;
    float* lbacc = (float*)(ws + off); off += 256;
    u16* WFT  = (u16*)(ws + off); off += 819200UL;     // WfT [256][1600]
    u16* W1T  = (u16*)(ws + off); off += 1048576UL;    // [E][512][256]
    u16* W2T  = (u16*)(ws + off); off += 1048576UL;    // [E][256][512]
    u16* W3T  = (u16*)(ws + off); off += 524288UL;     // [E][256][256]
    u16* XBF  = (u16*)(ws + off); off += 8388608UL;    // x bf16 [B][256]
    float* WR = (float*)(ws + off); off += 262144UL;   // gate weights [B][4]
    u16* H1   = (u16*)(ws + off); off += 67108864UL;   // [E][B][512]
    u16* H2   = (u16*)(ws + off); off += 33554432UL;   // [E][B][256]
    if (ws_size < off) return;

    prep_kernel<<<1681, 256, 0, stream>>>(Wf, W1, W2, W3, WFT, W1T, W2T, W3T, lbacc);
    fusion_kernel<<<512, 512, 0, stream>>>(vis, lang, state, WFT, bf_, gf, bfln, Wg,
                                           XBF, WR, lbacc);
    expert_gemm_kernel<<<dim3(128, 2, 4), 512, 0, stream>>>(
        XBF, 256, 0, W1T, 131072, b1, 512, H1, 512, 8388608UL);
    expert_gemm_kernel<<<dim3(128, 1, 4), 512, 0, stream>>>(
        H1, 512, 8388608UL, W2T, 131072, b2, 256, H2, 256, 4194304UL);
    combine_kernel<<<512, 256, 0, stream>>>(H2, W3T, b3, eg, eb, XBF, WR, lbacc, outp);
}